// Round 4
// baseline (1791.352 us; speedup 1.0000x reference)
//
#include <hip/hip_runtime.h>

// Sinkhorn divergence, 512 independent 256-point problems, 24 annealing steps.
// Round 4: max-pass eliminated. Shift for the shifted-logsumexp is predicted
// from the previous step's exact logsumexp L plus a block-wide bound on the
// column-potential change:
//   m'_i <= LA2 + rho*(L_i - LA2) + dmax*inv_new     (rho = eps_old/eps_new)
// This is a rigorous upper bound (max <= logsumexp; potential-change term is
// maximized over columns), so no overflow. Underflow (bound slack > ~120
// log2-units) is detected via sum thresholds; affected rows privately redo
// an exact 2-pass over all 256 columns (both halves' column data is in LDS).
// Step 0 uses shift = LA2 (valid: C_ij <= diameter^2 = eps0).
//
// Structure: 512-thread blocks, columns split in halves (h = tid>>8), rows
// duplicated x2, partial sums combined via LDS. 3 barriers/step.

constexpr int   N       = 256;   // points per cloud
constexpr int   NPROB   = 512;   // B*S*NR
constexpr int   NRDIM   = 64;
constexpr float DT_F    = 0.001f;
constexpr float EPS_MIN = 1e-4f; // BLUR^P
constexpr int   NSTEPS  = 24;
constexpr float LOG2E   = 1.4426950408889634f;
constexpr float LN2     = 0.6931471805599453f;
constexpr int   NTH     = 512;   // threads per block
constexpr int   CPH     = 128;   // columns per half
constexpr float LA2     = -8.0f; // log2(1/256)

extern "C" __global__ void __launch_bounds__(NTH, 4)
sinkhorn_div_kernel(const float* __restrict__ syn,
                    const float* __restrict__ obs,
                    float* __restrict__ divs)
{
    const int p   = blockIdx.x;          // ((b*S + s)*NR + r)
    const int r   = p & (NRDIM - 1);
    const int bs  = p >> 6;
    const int tid = threadIdx.x;
    const int row = tid & (N - 1);       // row index i (duplicated x2)
    const int h   = tid >> 8;            // column half 0..1

    __shared__ float4 ya[N];             // (Hxy, Hyy, y_j*inv, 0)
    __shared__ float4 xa[N];             // (Hyx, Hxx, x_j*inv, 0)
    __shared__ float4 ssh[NTH];          // per-thread partial sums
    __shared__ float  redA[32];
    __shared__ float4 redB[8];           // per-wave pot-change maxima

    const size_t base = (size_t)bs * N * NRDIM + r;
    const float xi = obs[base + (size_t)row * NRDIM];   // x cloud = obs
    const float yi = syn[base + (size_t)row * NRDIM];   // y cloud = syn

    // ---- block reductions: diameter (max/min) + all-zero mask sums ----
    float hi = fmaxf(xi, yi), lo = fminf(xi, yi);
    float ax = fabsf(xi),     ay = fabsf(yi);
    #pragma unroll
    for (int off = 32; off > 0; off >>= 1) {
        hi  = fmaxf(hi, __shfl_down(hi, off, 64));
        lo  = fminf(lo, __shfl_down(lo, off, 64));
        ax += __shfl_down(ax, off, 64);
        ay += __shfl_down(ay, off, 64);
    }
    const int wave = tid >> 6;           // 0..7
    if ((tid & 63) == 0) {
        redA[wave * 4 + 0] = hi;  redA[wave * 4 + 1] = lo;
        redA[wave * 4 + 2] = ax;  redA[wave * 4 + 3] = ay;
    }
    __syncthreads();
    float vmax = -3.4e38f, vmin = 3.4e38f, sax = 0.0f, say = 0.0f;
    #pragma unroll
    for (int w = 0; w < 8; ++w) {
        vmax = fmaxf(vmax, redA[w * 4 + 0]);
        vmin = fminf(vmin, redA[w * 4 + 1]);
        sax += redA[w * 4 + 2];
        say += redA[w * 4 + 3];
    }

    const float tspread  = 255.0f * DT_F;
    const float diameter = fmaxf(tspread, vmax - vmin);
    float eps_raw = diameter * diameter;              // eps0 = diameter^2

    const float ti    = (float)row * DT_F;
    const float selfx = 0.5f * (ti * ti + xi * xi);
    const float selfy = 0.5f * (ti * ti + yi * yi);

    float f = 0.0f, g = 0.0f, px = 0.0f, py = 0.0f;
    float L0 = 0.f, L1 = 0.f, L2 = 0.f, L3 = 0.f;       // prev logsumexp
    float dgmax = 0.f, dfmax = 0.f, dpxmax = 0.f, dpymax = 0.f;
    float eps_prev = 1.0f;

    const int j0 = h * CPH;

    for (int step = 0; step < NSTEPS; ++step) {
        const float eps = fmaxf(eps_raw, EPS_MIN);
        const float inv = LOG2E / eps;

        // ---- predicted safe shifts (upper bounds on the row maxima) ----
        float SH0, SH1, SH2, SH3;
        if (step == 0) {
            SH0 = SH1 = SH2 = SH3 = LA2;
        } else {
            const float rho = eps_prev / eps;
            SH0 = LA2 + rho * (L0 - LA2) + dgmax  * inv;   // xy: cols carry g
            SH1 = LA2 + rho * (L1 - LA2) + dfmax  * inv;   // yx: cols carry f
            SH2 = LA2 + rho * (L2 - LA2) + dpxmax * inv;   // xx: cols carry px
            SH3 = LA2 + rho * (L3 - LA2) + dpymax * inv;   // yy: cols carry py
        }

        // ---- prologue: half 0 provides column j = row of all arrays ----
        if (h == 0) {
            const float Hxy = fmaf(g  - selfy, inv, LA2);
            const float Hyy = fmaf(py - selfy, inv, LA2);
            const float Hyx = fmaf(f  - selfx, inv, LA2);
            const float Hxx = fmaf(px - selfx, inv, LA2);
            ya[row] = make_float4(Hxy, Hyy, yi * inv, 0.0f);
            xa[row] = make_float4(Hyx, Hxx, xi * inv, 0.0f);
        }
        __syncthreads();   // S1

        const float a = ti * DT_F * inv;      // t-term increment per j

        // ---- single pass: shifted sums over this half's columns ----
        float s0 = 0.0f, s1 = 0.0f, s2 = 0.0f, s3 = 0.0f;
        {
            const float rbase = a * (float)j0;
            float r0 = rbase - SH0, r1 = rbase - SH1;
            float r2 = rbase - SH2, r3 = rbase - SH3;
            #pragma unroll 4
            for (int j = j0; j < j0 + CPH; ++j) {
                const float4 yA = ya[j];
                const float4 xA = xa[j];
                s0 += __builtin_amdgcn_exp2f(fmaf(xi, yA.z, yA.x + r0));
                s3 += __builtin_amdgcn_exp2f(fmaf(yi, yA.z, yA.y + r3));
                s1 += __builtin_amdgcn_exp2f(fmaf(yi, xA.z, xA.x + r1));
                s2 += __builtin_amdgcn_exp2f(fmaf(xi, xA.z, xA.y + r2));
                r0 += a; r1 += a; r2 += a; r3 += a;
            }
        }
        ssh[tid] = make_float4(s0, s1, s2, s3);
        __syncthreads();   // S2

        // ---- combine halves (fixed order -> deterministic) ----
        {
            const float4 sa = ssh[row];
            const float4 sb = ssh[row + 256];
            s0 = sa.x + sb.x;  s1 = sa.y + sb.y;
            s2 = sa.z + sb.z;  s3 = sa.w + sb.w;
        }

        // ---- safety net: rare rows with excessive bound slack redo exact ----
        const bool bad = !(s0 >= 1e-36f && s0 <= 1e38f)
                      || !(s1 >= 1e-36f && s1 <= 1e38f)
                      || !(s2 >= 1e-36f && s2 <= 1e38f)
                      || !(s3 >= 1e-36f && s3 <= 1e38f);
        if (__builtin_expect(bad, 0)) {
            // private full-range exact 2-pass (no barriers needed)
            float m0 = -3.4e38f, m1 = -3.4e38f, m2 = -3.4e38f, m3 = -3.4e38f;
            float rr = 0.0f;
            for (int j = 0; j < N; ++j) {
                const float4 yA = ya[j];
                const float4 xA = xa[j];
                m0 = fmaxf(m0, fmaf(xi, yA.z, yA.x + rr));
                m3 = fmaxf(m3, fmaf(yi, yA.z, yA.y + rr));
                m1 = fmaxf(m1, fmaf(yi, xA.z, xA.x + rr));
                m2 = fmaxf(m2, fmaf(xi, xA.z, xA.y + rr));
                rr += a;
            }
            SH0 = m0; SH1 = m1; SH2 = m2; SH3 = m3;
            s0 = s1 = s2 = s3 = 0.0f;
            float r0 = -m0, r1 = -m1, r2 = -m2, r3 = -m3;
            for (int j = 0; j < N; ++j) {
                const float4 yA = ya[j];
                const float4 xA = xa[j];
                s0 += __builtin_amdgcn_exp2f(fmaf(xi, yA.z, yA.x + r0));
                s3 += __builtin_amdgcn_exp2f(fmaf(yi, yA.z, yA.y + r3));
                s1 += __builtin_amdgcn_exp2f(fmaf(yi, xA.z, xA.x + r1));
                s2 += __builtin_amdgcn_exp2f(fmaf(xi, xA.z, xA.y + r2));
                r0 += a; r1 += a; r2 += a; r3 += a;
            }
        }

        // ---- epilogue: exact logsumexp L (valid for any shift) ----
        L0 = SH0 + __builtin_amdgcn_logf(s0);   // v_log_f32 = log2
        L1 = SH1 + __builtin_amdgcn_logf(s1);
        L2 = SH2 + __builtin_amdgcn_logf(s2);
        L3 = SH3 + __builtin_amdgcn_logf(s3);
        const float el2 = eps * LN2;
        const float fn  = selfx - el2 * L0;
        const float gn  = selfy - el2 * L1;
        const float pxn = 0.5f * (px + (selfx - el2 * L2));
        const float pyn = 0.5f * (py + (selfy - el2 * L3));
        float ddf = fn - f, ddg = gn - g, ddpx = pxn - px, ddpy = pyn - py;
        f = fn; g = gn; px = pxn; py = pyn;

        // ---- block maxima of the column-potential changes (for next shift) ----
        #pragma unroll
        for (int off = 32; off > 0; off >>= 1) {
            ddf  = fmaxf(ddf,  __shfl_down(ddf,  off, 64));
            ddg  = fmaxf(ddg,  __shfl_down(ddg,  off, 64));
            ddpx = fmaxf(ddpx, __shfl_down(ddpx, off, 64));
            ddpy = fmaxf(ddpy, __shfl_down(ddpy, off, 64));
        }
        if ((tid & 63) == 0) redB[wave] = make_float4(ddf, ddg, ddpx, ddpy);
        __syncthreads();   // S3 (also orders ya/xa reads before next prologue)
        dfmax = -3.4e38f; dgmax = -3.4e38f; dpxmax = -3.4e38f; dpymax = -3.4e38f;
        #pragma unroll
        for (int w = 0; w < 8; ++w) {
            const float4 q = redB[w];
            dfmax  = fmaxf(dfmax,  q.x);
            dgmax  = fmaxf(dgmax,  q.y);
            dpxmax = fmaxf(dpxmax, q.z);
            dpymax = fmaxf(dpymax, q.w);
        }

        eps_prev = eps;
        eps_raw *= 0.25f;
    }

    // ---- divergence: (1/n) * sum_i [(f-px)+(g-py)], rows duplicated x2 ----
    float contrib = (f - px) + (g - py);
    #pragma unroll
    for (int off = 32; off > 0; off >>= 1)
        contrib += __shfl_down(contrib, off, 64);
    __syncthreads();                      // redA reuse
    if ((tid & 63) == 0) redA[wave] = contrib;
    __syncthreads();
    if (tid == 0) {
        float total = 0.0f;
        #pragma unroll
        for (int w = 0; w < 8; ++w) total += redA[w];
        total *= (1.0f / (float)(2 * N));             // x2 duplication
        const bool masked_out = (sax == 0.0f) && (say == 0.0f);
        divs[p] = masked_out ? 0.0f : total;
    }
}

extern "C" __global__ void __launch_bounds__(256)
reduce_out_kernel(const float* __restrict__ divs, float* __restrict__ out)
{
    const int b   = blockIdx.x;
    const int tid = threadIdx.x;
    __shared__ float red[4];
    float v = divs[b * 256 + tid];        // 256 = S*NR problems per batch
    #pragma unroll
    for (int off = 32; off > 0; off >>= 1)
        v += __shfl_down(v, off, 64);
    if ((tid & 63) == 0) red[tid >> 6] = v;
    __syncthreads();
    if (tid == 0) out[b] = red[0] + red[1] + red[2] + red[3];
}

extern "C" void kernel_launch(void* const* d_in, const int* in_sizes, int n_in,
                              void* d_out, int out_size, void* d_ws, size_t ws_size,
                              hipStream_t stream) {
    const float* syn = (const float*)d_in[0];   // syn_data
    const float* obs = (const float*)d_in[1];   // obs_data
    float* divs = (float*)d_ws;                 // 512 floats scratch

    sinkhorn_div_kernel<<<NPROB, NTH, 0, stream>>>(syn, obs, divs);
    reduce_out_kernel<<<2, 256, 0, stream>>>(divs, (float*)d_out);
}

// Round 5
// 1460.159 us; speedup vs baseline: 1.2268x; 1.2268x over previous
//
#include <hip/hip_runtime.h>

// Sinkhorn divergence, 512 independent 256-point problems, 24 annealing steps.
// Round 5: single-pass shifted logsumexp with a LOWER-BOUND shift
// (underflow impossible; overflow -> rare per-row exact redo), packed-f32
// (v_pk_fma_f32 / v_pk_add_f32 via float2 ext-vectors) over column pairs,
// and a pair-packed LDS layout (3 x b128 per 2 columns, single pass).
//
//   arg_ij = LA2 + (pot_j - C_ij)*inv,  inv = log2e/eps
//          = H_j + t_i*t_j*inv + v_i*w_j      (t-term affine in j -> running r)
//   L_i    = SH_i + log2( sum_j 2^{arg_ij - SH_i} )   exact for ANY shift
// Shift prediction (rho = eps_prev/eps_new):
//   m'_i >= LA2 + rho*(m_i-LA2) + dmin*inv' >= LA2 + rho*(L_i-8-LA2) + dmin*inv' = SH
//   (m_i <= L_i <= m_i+8; dmin = block-min of column-potential change)
// => SH <= m' => dominant exp term >= 1 => sum in [1, 256*2^{m'-SH}]; only
// overflow (sum=inf) needs the exact fallback. Step 0: SH = LA2 (args in
// [LA2-1.45, LA2] since C <= diameter^2 = eps0).

typedef float v2f __attribute__((ext_vector_type(2)));

constexpr int   N       = 256;   // points per cloud
constexpr int   NPROB   = 512;   // B*S*NR
constexpr int   NRDIM   = 64;
constexpr float DT_F    = 0.001f;
constexpr float EPS_MIN = 1e-4f; // BLUR^P
constexpr int   NSTEPS  = 24;
constexpr float LOG2E   = 1.4426950408889634f;
constexpr float LN2     = 0.6931471805599453f;
constexpr int   NTH     = 512;   // threads per block
constexpr int   PPH     = 64;    // column-pairs per half
constexpr float LA2     = -8.0f; // log2(1/256)

extern "C" __global__ void __launch_bounds__(NTH, 4)
sinkhorn_div_kernel(const float* __restrict__ syn,
                    const float* __restrict__ obs,
                    float* __restrict__ divs)
{
    const int p   = blockIdx.x;          // ((b*S + s)*NR + r)
    const int r   = p & (NRDIM - 1);
    const int bs  = p >> 6;
    const int tid = threadIdx.x;
    const int row = tid & (N - 1);       // row index i (duplicated x2)
    const int h   = tid >> 8;            // column half 0..1

    // pair-packed column data: pair q holds columns 2q, 2q+1
    __shared__ float4 arrA[N / 2];       // (Hxy0,Hxy1, Hyy0,Hyy1)
    __shared__ float4 arrB[N / 2];       // (wy0, wy1,  Hyx0,Hyx1)
    __shared__ float4 arrC[N / 2];       // (Hxx0,Hxx1, wx0, wx1)
    __shared__ float4 ssh[NTH];          // per-thread partial sums
    __shared__ float  redA[32];
    __shared__ float4 redB[8];           // per-wave pot-change minima

    const size_t base = (size_t)bs * N * NRDIM + r;
    const float xi = obs[base + (size_t)row * NRDIM];   // x cloud = obs
    const float yi = syn[base + (size_t)row * NRDIM];   // y cloud = syn

    // ---- block reductions: diameter (max/min) + all-zero mask sums ----
    float hi = fmaxf(xi, yi), lo = fminf(xi, yi);
    float ax = fabsf(xi),     ay = fabsf(yi);
    #pragma unroll
    for (int off = 32; off > 0; off >>= 1) {
        hi  = fmaxf(hi, __shfl_down(hi, off, 64));
        lo  = fminf(lo, __shfl_down(lo, off, 64));
        ax += __shfl_down(ax, off, 64);
        ay += __shfl_down(ay, off, 64);
    }
    const int wave = tid >> 6;           // 0..7
    if ((tid & 63) == 0) {
        redA[wave * 4 + 0] = hi;  redA[wave * 4 + 1] = lo;
        redA[wave * 4 + 2] = ax;  redA[wave * 4 + 3] = ay;
    }
    __syncthreads();
    float vmax = -3.4e38f, vmin = 3.4e38f, sax = 0.0f, say = 0.0f;
    #pragma unroll
    for (int w = 0; w < 8; ++w) {
        vmax = fmaxf(vmax, redA[w * 4 + 0]);
        vmin = fminf(vmin, redA[w * 4 + 1]);
        sax += redA[w * 4 + 2];
        say += redA[w * 4 + 3];
    }

    const float tspread  = 255.0f * DT_F;
    const float diameter = fmaxf(tspread, vmax - vmin);
    float eps_raw = diameter * diameter;              // eps0 = diameter^2

    const float ti    = (float)row * DT_F;
    const float selfx = 0.5f * (ti * ti + xi * xi);
    const float selfy = 0.5f * (ti * ti + yi * yi);

    float f = 0.0f, g = 0.0f, px = 0.0f, py = 0.0f;
    float L0 = 0.f, L1 = 0.f, L2 = 0.f, L3 = 0.f;     // prev exact logsumexp
    float dgmin = 0.f, dfmin = 0.f, dpxmin = 0.f, dpymin = 0.f;
    float eps_prev = 1.0f;

    const int q0 = h * PPH;              // first pair of this half

    for (int step = 0; step < NSTEPS; ++step) {
        const float eps = fmaxf(eps_raw, EPS_MIN);
        const float inv = LOG2E / eps;

        // ---- predicted safe shifts (lower bounds on the row maxima) ----
        float SH0, SH1, SH2, SH3;
        if (step == 0) {
            SH0 = SH1 = SH2 = SH3 = LA2;
        } else {
            const float rho = eps_prev / eps;
            SH0 = fmaf(rho, L0 - 8.0f - LA2, LA2) + dgmin  * inv;  // xy: cols g
            SH1 = fmaf(rho, L1 - 8.0f - LA2, LA2) + dfmin  * inv;  // yx: cols f
            SH2 = fmaf(rho, L2 - 8.0f - LA2, LA2) + dpxmin * inv;  // xx: cols px
            SH3 = fmaf(rho, L3 - 8.0f - LA2, LA2) + dpymin * inv;  // yy: cols py
        }

        // ---- prologue: half 0, column j = row, writes 6 packed slots ----
        if (h == 0) {
            const float Hxy = fmaf(g  - selfy, inv, LA2);
            const float Hyy = fmaf(py - selfy, inv, LA2);
            const float Hyx = fmaf(f  - selfx, inv, LA2);
            const float Hxx = fmaf(px - selfx, inv, LA2);
            const int   qq  = row >> 1;
            const int   o   = row & 1;
            float* pA = (float*)&arrA[qq];
            float* pB = (float*)&arrB[qq];
            float* pC = (float*)&arrC[qq];
            pA[o]     = Hxy;      pA[2 + o] = Hyy;
            pB[o]     = yi * inv; pB[2 + o] = Hyx;
            pC[o]     = Hxx;      pC[2 + o] = xi * inv;
        }
        __syncthreads();   // S1

        const float a = ti * DT_F * inv;      // t-term increment per column

        // ---- single packed pass over this half's column pairs ----
        float S0, S1, S2, S3;
        {
            const float cb = a * (float)(2 * q0);
            v2f r0 = {cb - SH0, cb + a - SH0};
            v2f r1 = {cb - SH1, cb + a - SH1};
            v2f r2 = {cb - SH2, cb + a - SH2};
            v2f r3 = {cb - SH3, cb + a - SH3};
            const v2f stp = {2.0f * a, 2.0f * a};
            const v2f xi2 = {xi, xi};
            const v2f yi2 = {yi, yi};
            v2f s0 = {0.f, 0.f}, s1 = {0.f, 0.f}, s2 = {0.f, 0.f}, s3 = {0.f, 0.f};
            #pragma unroll 2
            for (int q = q0; q < q0 + PPH; ++q) {
                const float4 A = arrA[q];
                const float4 B = arrB[q];
                const float4 C = arrC[q];
                const v2f hxy = {A.x, A.y}, hyy = {A.z, A.w};
                const v2f wy  = {B.x, B.y}, hyx = {B.z, B.w};
                const v2f hxx = {C.x, C.y}, wx  = {C.z, C.w};
                const v2f axy = __builtin_elementwise_fma(xi2, wy, hxy + r0);
                const v2f ayx = __builtin_elementwise_fma(yi2, wx, hyx + r1);
                const v2f axx = __builtin_elementwise_fma(xi2, wx, hxx + r2);
                const v2f ayy = __builtin_elementwise_fma(yi2, wy, hyy + r3);
                s0 += (v2f){__builtin_amdgcn_exp2f(axy.x), __builtin_amdgcn_exp2f(axy.y)};
                s1 += (v2f){__builtin_amdgcn_exp2f(ayx.x), __builtin_amdgcn_exp2f(ayx.y)};
                s2 += (v2f){__builtin_amdgcn_exp2f(axx.x), __builtin_amdgcn_exp2f(axx.y)};
                s3 += (v2f){__builtin_amdgcn_exp2f(ayy.x), __builtin_amdgcn_exp2f(ayy.y)};
                r0 += stp; r1 += stp; r2 += stp; r3 += stp;
            }
            S0 = s0.x + s0.y;  S1 = s1.x + s1.y;
            S2 = s2.x + s2.y;  S3 = s3.x + s3.y;
        }
        ssh[tid] = make_float4(S0, S1, S2, S3);
        __syncthreads();   // S2

        // ---- combine halves (fixed order -> deterministic) ----
        {
            const float4 sa = ssh[row];
            const float4 sb = ssh[row + 256];
            S0 = sa.x + sb.x;  S1 = sa.y + sb.y;
            S2 = sa.z + sb.z;  S3 = sa.w + sb.w;
        }

        // ---- overflow-only fallback: exact per-row 2-pass (rare) ----
        const bool bad = !(S0 <= 3.0e38f) || !(S1 <= 3.0e38f)
                      || !(S2 <= 3.0e38f) || !(S3 <= 3.0e38f);
        if (__builtin_expect(bad, 0)) {
            float m0 = -3.4e38f, m1 = -3.4e38f, m2 = -3.4e38f, m3 = -3.4e38f;
            for (int q = 0; q < N / 2; ++q) {
                const float4 A = arrA[q];
                const float4 B = arrB[q];
                const float4 C = arrC[q];
                const float c0 = a * (float)(2 * q);
                const float c1 = c0 + a;
                m0 = fmaxf(m0, fmaxf(fmaf(xi, B.x, A.x + c0), fmaf(xi, B.y, A.y + c1)));
                m1 = fmaxf(m1, fmaxf(fmaf(yi, C.z, B.z + c0), fmaf(yi, C.w, B.w + c1)));
                m2 = fmaxf(m2, fmaxf(fmaf(xi, C.z, C.x + c0), fmaf(xi, C.w, C.y + c1)));
                m3 = fmaxf(m3, fmaxf(fmaf(yi, B.x, A.z + c0), fmaf(yi, B.y, A.w + c1)));
            }
            SH0 = m0; SH1 = m1; SH2 = m2; SH3 = m3;
            S0 = S1 = S2 = S3 = 0.0f;
            for (int q = 0; q < N / 2; ++q) {
                const float4 A = arrA[q];
                const float4 B = arrB[q];
                const float4 C = arrC[q];
                const float c0 = a * (float)(2 * q);
                const float c1 = c0 + a;
                S0 += __builtin_amdgcn_exp2f(fmaf(xi, B.x, A.x + c0 - m0))
                    + __builtin_amdgcn_exp2f(fmaf(xi, B.y, A.y + c1 - m0));
                S1 += __builtin_amdgcn_exp2f(fmaf(yi, C.z, B.z + c0 - m1))
                    + __builtin_amdgcn_exp2f(fmaf(yi, C.w, B.w + c1 - m1));
                S2 += __builtin_amdgcn_exp2f(fmaf(xi, C.z, C.x + c0 - m2))
                    + __builtin_amdgcn_exp2f(fmaf(xi, C.w, C.y + c1 - m2));
                S3 += __builtin_amdgcn_exp2f(fmaf(yi, B.x, A.z + c0 - m3))
                    + __builtin_amdgcn_exp2f(fmaf(yi, B.y, A.w + c1 - m3));
            }
        }

        // ---- epilogue: exact logsumexp L (valid for any shift) ----
        L0 = SH0 + __builtin_amdgcn_logf(S0);   // v_log_f32 = log2
        L1 = SH1 + __builtin_amdgcn_logf(S1);
        L2 = SH2 + __builtin_amdgcn_logf(S2);
        L3 = SH3 + __builtin_amdgcn_logf(S3);
        const float el2 = eps * LN2;
        const float fn  = selfx - el2 * L0;
        const float gn  = selfy - el2 * L1;
        const float pxn = 0.5f * (px + (selfx - el2 * L2));
        const float pyn = 0.5f * (py + (selfy - el2 * L3));
        float ddf = fn - f, ddg = gn - g, ddpx = pxn - px, ddpy = pyn - py;
        f = fn; g = gn; px = pxn; py = pyn;

        // ---- block MINIMA of the column-potential changes (next shift) ----
        #pragma unroll
        for (int off = 32; off > 0; off >>= 1) {
            ddf  = fminf(ddf,  __shfl_down(ddf,  off, 64));
            ddg  = fminf(ddg,  __shfl_down(ddg,  off, 64));
            ddpx = fminf(ddpx, __shfl_down(ddpx, off, 64));
            ddpy = fminf(ddpy, __shfl_down(ddpy, off, 64));
        }
        if ((tid & 63) == 0) redB[wave] = make_float4(ddf, ddg, ddpx, ddpy);
        __syncthreads();   // S3 (also orders arr* reads before next prologue)
        dfmin = 3.4e38f; dgmin = 3.4e38f; dpxmin = 3.4e38f; dpymin = 3.4e38f;
        #pragma unroll
        for (int w = 0; w < 8; ++w) {
            const float4 qv = redB[w];
            dfmin  = fminf(dfmin,  qv.x);
            dgmin  = fminf(dgmin,  qv.y);
            dpxmin = fminf(dpxmin, qv.z);
            dpymin = fminf(dpymin, qv.w);
        }

        eps_prev = eps;
        eps_raw *= 0.25f;
    }

    // ---- divergence: (1/n) * sum_i [(f-px)+(g-py)], rows duplicated x2 ----
    float contrib = (f - px) + (g - py);
    #pragma unroll
    for (int off = 32; off > 0; off >>= 1)
        contrib += __shfl_down(contrib, off, 64);
    __syncthreads();                      // redA reuse
    if ((tid & 63) == 0) redA[wave] = contrib;
    __syncthreads();
    if (tid == 0) {
        float total = 0.0f;
        #pragma unroll
        for (int w = 0; w < 8; ++w) total += redA[w];
        total *= (1.0f / (float)(2 * N));             // x2 duplication
        const bool masked_out = (sax == 0.0f) && (say == 0.0f);
        divs[p] = masked_out ? 0.0f : total;
    }
}

extern "C" __global__ void __launch_bounds__(256)
reduce_out_kernel(const float* __restrict__ divs, float* __restrict__ out)
{
    const int b   = blockIdx.x;
    const int tid = threadIdx.x;
    __shared__ float red[4];
    float v = divs[b * 256 + tid];        // 256 = S*NR problems per batch
    #pragma unroll
    for (int off = 32; off > 0; off >>= 1)
        v += __shfl_down(v, off, 64);
    if ((tid & 63) == 0) red[tid >> 6] = v;
    __syncthreads();
    if (tid == 0) out[b] = red[0] + red[1] + red[2] + red[3];
}

extern "C" void kernel_launch(void* const* d_in, const int* in_sizes, int n_in,
                              void* d_out, int out_size, void* d_ws, size_t ws_size,
                              hipStream_t stream) {
    const float* syn = (const float*)d_in[0];   // syn_data
    const float* obs = (const float*)d_in[1];   // obs_data
    float* divs = (float*)d_ws;                 // 512 floats scratch

    sinkhorn_div_kernel<<<NPROB, NTH, 0, stream>>>(syn, obs, divs);
    reduce_out_kernel<<<2, 256, 0, stream>>>(divs, (float*)d_out);
}

// Round 6
// 1333.978 us; speedup vs baseline: 1.3429x; 1.0946x over previous
//
#include <hip/hip_runtime.h>

// Sinkhorn divergence, 512 independent 256-point problems, 24 annealing steps.
// Round 6: single-pass shifted logsumexp with in-loop exact max tracking.
//   arg_ij = LA2 + (pot_j - C_ij)*inv,  inv = log2e/eps   (log2 domain)
//          = H_j + (t_i*t_j)*inv + v_i*w_j   (t-term affine in j -> running r)
// Per step, per matrix: e_j = arg_j - SH computed once; sum 2^e AND max e
// tracked in the same loop -> exact row max M = SH + m_rel known every step.
// Next-step shift (rho = eps_prev/eps >= 1, dmin = block-min column-potential
// change):  SH' = LA2 + rho*(M - LA2) + dmin*inv'  <= m'  (rigorous lower
// bound: arg'_j = LA2 + rho*(arg_j - LA2) + dpot_j*inv') => sum >= 1, no
// underflow ever. Overflow only if slack m_rel > ~100: rare; handled by a
// barrier-free per-thread redo over all 256 columns using the exact max as
// shift (no max pass needed). Step 0: SH = LA2 (args in [LA2-1.45, LA2]).
// Structure: 512 threads, column halves (h=tid>>8), rows duplicated x2,
// R3's conflict-free float4 LDS layout, 3 barriers/step.

constexpr int   N       = 256;   // points per cloud
constexpr int   NPROB   = 512;   // B*S*NR
constexpr int   NRDIM   = 64;
constexpr float DT_F    = 0.001f;
constexpr float EPS_MIN = 1e-4f; // BLUR^P
constexpr int   NSTEPS  = 24;
constexpr float LOG2E   = 1.4426950408889634f;
constexpr float LN2     = 0.6931471805599453f;
constexpr int   NTH     = 512;   // threads per block
constexpr int   CPH     = 128;   // columns per half
constexpr float LA2     = -8.0f; // log2(1/256)

extern "C" __global__ void __launch_bounds__(NTH, 4)
sinkhorn_div_kernel(const float* __restrict__ syn,
                    const float* __restrict__ obs,
                    float* __restrict__ divs)
{
    const int p   = blockIdx.x;          // ((b*S + s)*NR + r)
    const int r   = p & (NRDIM - 1);
    const int bs  = p >> 6;
    const int tid = threadIdx.x;
    const int row = tid & (N - 1);       // row index i (duplicated x2)
    const int h   = tid >> 8;            // column half 0..1

    __shared__ float4 ya[N];             // (Hxy, Hyy, y_j*inv, 0)
    __shared__ float4 xa[N];             // (Hyx, Hxx, x_j*inv, 0)
    __shared__ float4 ssh[NTH];          // per-thread partial sums
    __shared__ float4 msh[NTH];          // per-thread partial max(e)
    __shared__ float  redA[32];
    __shared__ float4 redB[8];           // per-wave pot-change minima

    const size_t base = (size_t)bs * N * NRDIM + r;
    const float xi = obs[base + (size_t)row * NRDIM];   // x cloud = obs
    const float yi = syn[base + (size_t)row * NRDIM];   // y cloud = syn

    // ---- block reductions: diameter (max/min) + all-zero mask sums ----
    float hi = fmaxf(xi, yi), lo = fminf(xi, yi);
    float ax = fabsf(xi),     ay = fabsf(yi);
    #pragma unroll
    for (int off = 32; off > 0; off >>= 1) {
        hi  = fmaxf(hi, __shfl_down(hi, off, 64));
        lo  = fminf(lo, __shfl_down(lo, off, 64));
        ax += __shfl_down(ax, off, 64);
        ay += __shfl_down(ay, off, 64);
    }
    const int wave = tid >> 6;           // 0..7
    if ((tid & 63) == 0) {
        redA[wave * 4 + 0] = hi;  redA[wave * 4 + 1] = lo;
        redA[wave * 4 + 2] = ax;  redA[wave * 4 + 3] = ay;
    }
    __syncthreads();
    float vmax = -3.4e38f, vmin = 3.4e38f, sax = 0.0f, say = 0.0f;
    #pragma unroll
    for (int w = 0; w < 8; ++w) {
        vmax = fmaxf(vmax, redA[w * 4 + 0]);
        vmin = fminf(vmin, redA[w * 4 + 1]);
        sax += redA[w * 4 + 2];
        say += redA[w * 4 + 3];
    }

    const float tspread  = 255.0f * DT_F;
    const float diameter = fmaxf(tspread, vmax - vmin);
    float eps_raw = diameter * diameter;              // eps0 = diameter^2

    const float ti    = (float)row * DT_F;
    const float selfx = 0.5f * (ti * ti + xi * xi);
    const float selfy = 0.5f * (ti * ti + yi * yi);

    float f = 0.0f, g = 0.0f, px = 0.0f, py = 0.0f;
    float M0 = 0.f, M1 = 0.f, M2 = 0.f, M3 = 0.f;     // prev exact row maxima
    float dgmin = 0.f, dfmin = 0.f, dpxmin = 0.f, dpymin = 0.f;
    float eps_prev = 1.0f;

    const int j0 = h * CPH;

    for (int step = 0; step < NSTEPS; ++step) {
        const float eps = fmaxf(eps_raw, EPS_MIN);
        const float inv = LOG2E / eps;

        // ---- predicted shifts: rigorous lower bounds on the row maxima ----
        float SH0, SH1, SH2, SH3;
        if (step == 0) {
            SH0 = SH1 = SH2 = SH3 = LA2;
        } else {
            const float rho = eps_prev / eps;
            SH0 = fmaf(rho, M0 - LA2, LA2) + dgmin  * inv;  // xy: cols carry g
            SH1 = fmaf(rho, M1 - LA2, LA2) + dfmin  * inv;  // yx: cols carry f
            SH2 = fmaf(rho, M2 - LA2, LA2) + dpxmin * inv;  // xx: cols carry px
            SH3 = fmaf(rho, M3 - LA2, LA2) + dpymin * inv;  // yy: cols carry py
        }

        // ---- prologue: half 0 provides column j = row of all arrays ----
        if (h == 0) {
            const float Hxy = fmaf(g  - selfy, inv, LA2);
            const float Hyy = fmaf(py - selfy, inv, LA2);
            const float Hyx = fmaf(f  - selfx, inv, LA2);
            const float Hxx = fmaf(px - selfx, inv, LA2);
            ya[row] = make_float4(Hxy, Hyy, yi * inv, 0.0f);
            xa[row] = make_float4(Hyx, Hxx, xi * inv, 0.0f);
        }
        __syncthreads();   // S1

        const float a = ti * DT_F * inv;      // t-term increment per column

        // ---- single pass: shifted sums + in-loop max over this half ----
        float s0 = 0.f, s1 = 0.f, s2 = 0.f, s3 = 0.f;
        float mr0 = -3.4e38f, mr1 = -3.4e38f, mr2 = -3.4e38f, mr3 = -3.4e38f;
        {
            const float rbase = a * (float)j0;
            float r0 = rbase - SH0, r1 = rbase - SH1;
            float r2 = rbase - SH2, r3 = rbase - SH3;
            #pragma unroll 4
            for (int j = j0; j < j0 + CPH; ++j) {
                const float4 yA = ya[j];
                const float4 xA = xa[j];
                const float e0 = fmaf(xi, yA.z, yA.x + r0);   // xy
                const float e3 = fmaf(yi, yA.z, yA.y + r3);   // yy
                const float e1 = fmaf(yi, xA.z, xA.x + r1);   // yx
                const float e2 = fmaf(xi, xA.z, xA.y + r2);   // xx
                mr0 = fmaxf(mr0, e0);  s0 += __builtin_amdgcn_exp2f(e0);
                mr3 = fmaxf(mr3, e3);  s3 += __builtin_amdgcn_exp2f(e3);
                mr1 = fmaxf(mr1, e1);  s1 += __builtin_amdgcn_exp2f(e1);
                mr2 = fmaxf(mr2, e2);  s2 += __builtin_amdgcn_exp2f(e2);
                r0 += a; r1 += a; r2 += a; r3 += a;
            }
        }
        ssh[tid] = make_float4(s0, s1, s2, s3);
        msh[tid] = make_float4(mr0, mr1, mr2, mr3);
        __syncthreads();   // S2

        // ---- combine halves (fixed order -> deterministic) ----
        float S0, S1, S2, S3;
        {
            const float4 sa = ssh[row];
            const float4 sb = ssh[row + 256];
            S0 = sa.x + sb.x;  S1 = sa.y + sb.y;
            S2 = sa.z + sb.z;  S3 = sa.w + sb.w;
            const float4 ma = msh[row];
            const float4 mb = msh[row + 256];
            mr0 = fmaxf(ma.x, mb.x);  mr1 = fmaxf(ma.y, mb.y);
            mr2 = fmaxf(ma.z, mb.z);  mr3 = fmaxf(ma.w, mb.w);
        }

        // base for L: L = base + log2(S)
        float b0 = SH0, b1 = SH1, b2 = SH2, b3 = SH3;

        // ---- rare redo: slack too big (possible overflow). Barrier-free:
        // re-sum all 256 columns against the exact known max. NaN-safe check.
        const bool bad = !(mr0 <= 100.f) || !(mr1 <= 100.f)
                      || !(mr2 <= 100.f) || !(mr3 <= 100.f);
        if (__builtin_expect(bad, 0)) {
            b0 = SH0 + mr0; b1 = SH1 + mr1; b2 = SH2 + mr2; b3 = SH3 + mr3;
            S0 = S1 = S2 = S3 = 0.0f;
            float r0 = -b0, r1 = -b1, r2 = -b2, r3 = -b3;
            for (int j = 0; j < N; ++j) {
                const float4 yA = ya[j];
                const float4 xA = xa[j];
                S0 += __builtin_amdgcn_exp2f(fmaf(xi, yA.z, yA.x + r0));
                S3 += __builtin_amdgcn_exp2f(fmaf(yi, yA.z, yA.y + r3));
                S1 += __builtin_amdgcn_exp2f(fmaf(yi, xA.z, xA.x + r1));
                S2 += __builtin_amdgcn_exp2f(fmaf(xi, xA.z, xA.y + r2));
                r0 += a; r1 += a; r2 += a; r3 += a;
            }
        }

        // ---- exact row maxima for next step's shift prediction ----
        M0 = SH0 + mr0; M1 = SH1 + mr1; M2 = SH2 + mr2; M3 = SH3 + mr3;

        // ---- epilogue: exact logsumexp (valid for any shift, no overflow) ----
        const float L0 = b0 + __builtin_amdgcn_logf(S0);   // v_log_f32 = log2
        const float L1 = b1 + __builtin_amdgcn_logf(S1);
        const float L2 = b2 + __builtin_amdgcn_logf(S2);
        const float L3 = b3 + __builtin_amdgcn_logf(S3);
        const float el2 = eps * LN2;
        const float fn  = selfx - el2 * L0;
        const float gn  = selfy - el2 * L1;
        const float pxn = 0.5f * (px + (selfx - el2 * L2));
        const float pyn = 0.5f * (py + (selfy - el2 * L3));
        float ddf = fn - f, ddg = gn - g, ddpx = pxn - px, ddpy = pyn - py;
        f = fn; g = gn; px = pxn; py = pyn;

        // ---- block MINIMA of the column-potential changes (next shift) ----
        #pragma unroll
        for (int off = 32; off > 0; off >>= 1) {
            ddf  = fminf(ddf,  __shfl_down(ddf,  off, 64));
            ddg  = fminf(ddg,  __shfl_down(ddg,  off, 64));
            ddpx = fminf(ddpx, __shfl_down(ddpx, off, 64));
            ddpy = fminf(ddpy, __shfl_down(ddpy, off, 64));
        }
        if ((tid & 63) == 0) redB[wave] = make_float4(ddf, ddg, ddpx, ddpy);
        __syncthreads();   // S3 (also orders ya/xa reads before next prologue)
        dfmin = 3.4e38f; dgmin = 3.4e38f; dpxmin = 3.4e38f; dpymin = 3.4e38f;
        #pragma unroll
        for (int w = 0; w < 8; ++w) {
            const float4 qv = redB[w];
            dfmin  = fminf(dfmin,  qv.x);
            dgmin  = fminf(dgmin,  qv.y);
            dpxmin = fminf(dpxmin, qv.z);
            dpymin = fminf(dpymin, qv.w);
        }

        eps_prev = eps;
        eps_raw *= 0.25f;
    }

    // ---- divergence: (1/n) * sum_i [(f-px)+(g-py)], rows duplicated x2 ----
    float contrib = (f - px) + (g - py);
    #pragma unroll
    for (int off = 32; off > 0; off >>= 1)
        contrib += __shfl_down(contrib, off, 64);
    __syncthreads();                      // redA reuse
    if ((tid & 63) == 0) redA[wave] = contrib;
    __syncthreads();
    if (tid == 0) {
        float total = 0.0f;
        #pragma unroll
        for (int w = 0; w < 8; ++w) total += redA[w];
        total *= (1.0f / (float)(2 * N));             // x2 duplication
        const bool masked_out = (sax == 0.0f) && (say == 0.0f);
        divs[p] = masked_out ? 0.0f : total;
    }
}

extern "C" __global__ void __launch_bounds__(256)
reduce_out_kernel(const float* __restrict__ divs, float* __restrict__ out)
{
    const int b   = blockIdx.x;
    const int tid = threadIdx.x;
    __shared__ float red[4];
    float v = divs[b * 256 + tid];        // 256 = S*NR problems per batch
    #pragma unroll
    for (int off = 32; off > 0; off >>= 1)
        v += __shfl_down(v, off, 64);
    if ((tid & 63) == 0) red[tid >> 6] = v;
    __syncthreads();
    if (tid == 0) out[b] = red[0] + red[1] + red[2] + red[3];
}

extern "C" void kernel_launch(void* const* d_in, const int* in_sizes, int n_in,
                              void* d_out, int out_size, void* d_ws, size_t ws_size,
                              hipStream_t stream) {
    const float* syn = (const float*)d_in[0];   // syn_data
    const float* obs = (const float*)d_in[1];   // obs_data
    float* divs = (float*)d_ws;                 // 512 floats scratch

    sinkhorn_div_kernel<<<NPROB, NTH, 0, stream>>>(syn, obs, divs);
    reduce_out_kernel<<<2, 256, 0, stream>>>(divs, (float*)d_out);
}